// Round 10
// baseline (285.841 us; speedup 1.0000x reference)
//
#include <hip/hip_runtime.h>
#include <hip/hip_bf16.h>

typedef unsigned int uint32;
typedef __attribute__((ext_vector_type(8))) short bf16x8;
typedef __attribute__((ext_vector_type(4))) float f32x4;

#define MFMA(A, B, C) __builtin_amdgcn_mfma_f32_16x16x32_bf16(A, B, C, 0, 0, 0)

union FragU { uint32 u[4]; bf16x8 v; };
union BF8  { __hip_bfloat162 h2[4]; bf16x8 v; };

// 3-pass split (phase-1 z only): hi=trunc top16, lo=bf16(x-hi)
__device__ __forceinline__ void split8(f32x4 a, f32x4 b, bf16x8& hi, bf16x8& lo) {
    float e[8] = {a[0], a[1], a[2], a[3], b[0], b[1], b[2], b[3]};
    FragU H, L;
    #pragma unroll
    for (int q = 0; q < 4; ++q) {
        uint32 u0 = __float_as_uint(e[2*q]);
        uint32 u1 = __float_as_uint(e[2*q + 1]);
        uint32 h0 = u0 & 0xFFFF0000u;
        uint32 h1 = u1 & 0xFFFF0000u;
        float l0 = e[2*q]     - __uint_as_float(h0);
        float l1 = e[2*q + 1] - __uint_as_float(h1);
        H.u[q] = (h0 >> 16) | h1;
        L.u[q] = (__float_as_uint(l0) >> 16) | (__float_as_uint(l1) & 0xFFFF0000u);
    }
    hi = H.v; lo = L.v;
}

// ---- pre-kernel: split |Wp| and W2 into RNE hi/lo bf16 pairs in d_ws ----
__global__ __launch_bounds__(256) void split_weights(
    const float* __restrict__ Wp, const float* __restrict__ W2,
    __hip_bfloat16* __restrict__ wp_hi, __hip_bfloat16* __restrict__ wp_lo,
    __hip_bfloat16* __restrict__ w2_hi, __hip_bfloat16* __restrict__ w2_lo)
{
    const int i = blockIdx.x * 256 + threadIdx.x;
    if (i < 128 * 64) {
        float x = fabsf(Wp[i]);
        __hip_bfloat16 h = __float2bfloat16(x);          // RNE
        wp_hi[i] = h;
        wp_lo[i] = __float2bfloat16(x - __bfloat162float(h));
    }
    if (i < 128 * 1024) {
        float x = W2[i];
        __hip_bfloat16 h = __float2bfloat16(x);
        w2_hi[i] = h;
        w2_lo[i] = __float2bfloat16(x - __bfloat162float(h));
    }
}

// ---- Kernel A: Y = z @ |Wp|^T, stored TRANSPOSED Yt[d][n] (fp32) ----------
// 256 thr = 4 waves; block = 64 samples x all 128 d (wave wv owns 32 d).
__global__ __launch_bounds__(256) void decoder_y(
    const float* __restrict__ z,
    const __hip_bfloat16* __restrict__ wp_hi, const __hip_bfloat16* __restrict__ wp_lo,
    float* __restrict__ Yt)
{
    __shared__ float Y[4][64][33];

    const int t    = threadIdx.x;
    const int lane = t & 63;
    const int wv   = __builtin_amdgcn_readfirstlane(t >> 6);
    const int l15  = lane & 15;
    const int lg   = lane >> 4;
    const int n0   = blockIdx.x * 64;

    bf16x8 wh[2][2], wl[2][2];
    #pragma unroll
    for (int dt = 0; dt < 2; ++dt) {
        const int d = wv*32 + dt*16 + l15;
        #pragma unroll
        for (int kt = 0; kt < 2; ++kt) {
            const int off = d*64 + kt*32 + lg*8;
            wh[dt][kt] = *(const bf16x8*)(wp_hi + off);
            wl[dt][kt] = *(const bf16x8*)(wp_lo + off);
        }
    }
    #pragma unroll
    for (int nt = 0; nt < 4; ++nt) {
        bf16x8 zh[2], zl[2];
        #pragma unroll
        for (int kt = 0; kt < 2; ++kt) {
            const float* p = z + (size_t)(n0 + nt*16 + l15)*64 + kt*32 + lg*8;
            split8(*(const f32x4*)p, *(const f32x4*)(p + 4), zh[kt], zl[kt]);
        }
        #pragma unroll
        for (int dt = 0; dt < 2; ++dt) {
            f32x4 acc = {0.f, 0.f, 0.f, 0.f};
            #pragma unroll
            for (int kt = 0; kt < 2; ++kt) {
                acc = MFMA(zh[kt], wh[dt][kt], acc);   // hi*hi
                acc = MFMA(zl[kt], wh[dt][kt], acc);   // lo*hi
                acc = MFMA(zh[kt], wl[dt][kt], acc);   // hi*lo
            }
            #pragma unroll
            for (int r = 0; r < 4; ++r)
                Y[wv][nt*16 + lg*4 + r][dt*16 + l15] = acc[r];
        }
    }
    __syncthreads();

    // transpose-store: Yt[d][n0+lane], coalesced 256B per instr.
    // LDS column read stride 33 -> bank (lane*33)%32 = 2-way alias (free).
    #pragma unroll 4
    for (int j = 0; j < 32; ++j) {
        const int d = wv*32 + j;
        Yt[(size_t)d*65536 + n0 + lane] = Y[wv][lane][j];
    }
}

// ---- Kernel B: per-feature tiny MLPs. ZERO LDS, no barriers ---------------
// 256 thr = 4 fully independent waves; wave wv: 64 samples x features [32wv..).
// Occupancy capped only by VGPR -> target 8 waves/SIMD.
__global__ __launch_bounds__(256, 8) void decoder_mlp(
    const float* __restrict__ Yt,
    const __hip_bfloat16* __restrict__ w2_hi, const __hip_bfloat16* __restrict__ w2_lo,
    const float* __restrict__ W1, const float* __restrict__ b1,
    const float* __restrict__ b2,
    const float* __restrict__ W3, const float* __restrict__ b3,
    float* __restrict__ out)
{
    const int t    = threadIdx.x;
    const int lane = t & 63;
    const int g    = __builtin_amdgcn_readfirstlane(t >> 6);  // feature group
    const int l15  = lane & 15;
    const int lg   = lane >> 4;
    const int n0   = blockIdx.x * 64;

    #pragma unroll 2
    for (int j = 0; j < 32; ++j) {
        const int d = g*32 + j;                  // wave-uniform feature
        bf16x8 ah[2], al[2];
        #pragma unroll
        for (int rt = 0; rt < 2; ++rt) {
            const int off = d*1024 + (rt*16 + l15)*32 + lg*8;
            ah[rt] = *(const bf16x8*)(w2_hi + off);
            al[rt] = *(const bf16x8*)(w2_lo + off);
        }
        const f32x4 w1a = *(const f32x4*)(W1 + d*32 + lg*8);
        const f32x4 w1b = *(const f32x4*)(W1 + d*32 + lg*8 + 4);
        const f32x4 b1a = *(const f32x4*)(b1 + d*32 + lg*8);
        const f32x4 b1b = *(const f32x4*)(b1 + d*32 + lg*8 + 4);
        const f32x4 b2a = *(const f32x4*)(b2 + d*32 + lg*4);        // k2 = lg*4+r
        const f32x4 b2b = *(const f32x4*)(b2 + d*32 + 16 + lg*4);
        const f32x4 w3a = *(const f32x4*)(W3 + d*32 + lg*4);
        const f32x4 w3b = *(const f32x4*)(W3 + d*32 + 16 + lg*4);
        const float b3v = b3[d];

        // ---- 4 coalesced y loads (64B per 16-lane cluster, lg-broadcast) ----
        float yv[4];
        #pragma unroll
        for (int ct = 0; ct < 4; ++ct)
            yv[ct] = Yt[(size_t)d*65536 + n0 + ct*16 + l15];

        // ---- 4 independent layer1 + pack chains ----
        bf16x8 pk[4];
        #pragma unroll
        for (int ct = 0; ct < 4; ++ct) {
            const float y = yv[ct];
            float h0[4], h1v[4];
            #pragma unroll
            for (int i = 0; i < 4; ++i) h0[i]  = fmaxf(fmaf(y, w1a[i], b1a[i]), 0.f);
            #pragma unroll
            for (int i = 0; i < 4; ++i) h1v[i] = fmaxf(fmaf(y, w1b[i], b1b[i]), 0.f);
            BF8 r;
            r.h2[0] = __float22bfloat162_rn(make_float2(h0[0], h0[1]));
            r.h2[1] = __float22bfloat162_rn(make_float2(h0[2], h0[3]));
            r.h2[2] = __float22bfloat162_rn(make_float2(h1v[0], h1v[1]));
            r.h2[3] = __float22bfloat162_rn(make_float2(h1v[2], h1v[3]));
            pk[ct] = r.v;
        }

        // ---- 16 MFMAs: 8 hi first, then 8 lo (acc init = b2) ----
        f32x4 A0[4], A1[4];
        #pragma unroll
        for (int ct = 0; ct < 4; ++ct) { A0[ct] = b2a; A1[ct] = b2b; }
        #pragma unroll
        for (int ct = 0; ct < 4; ++ct) {
            A0[ct] = MFMA(ah[0], pk[ct], A0[ct]);
            A1[ct] = MFMA(ah[1], pk[ct], A1[ct]);
        }
        #pragma unroll
        for (int ct = 0; ct < 4; ++ct) {
            A0[ct] = MFMA(al[0], pk[ct], A0[ct]);
            A1[ct] = MFMA(al[1], pk[ct], A1[ct]);
        }

        // ---- 4 independent layer3 tails + direct store ----
        #pragma unroll
        for (int ct = 0; ct < 4; ++ct) {
            float s = fmaxf(A0[ct][0], 0.f) * w3a[0];
            s = fmaf(fmaxf(A0[ct][1], 0.f), w3a[1], s);
            s = fmaf(fmaxf(A0[ct][2], 0.f), w3a[2], s);
            s = fmaf(fmaxf(A0[ct][3], 0.f), w3a[3], s);
            s = fmaf(fmaxf(A1[ct][0], 0.f), w3b[0], s);
            s = fmaf(fmaxf(A1[ct][1], 0.f), w3b[1], s);
            s = fmaf(fmaxf(A1[ct][2], 0.f), w3b[2], s);
            s = fmaf(fmaxf(A1[ct][3], 0.f), w3b[3], s);
            s += __shfl_xor(s, 16);      // reduce over the 4 lg groups
            s += __shfl_xor(s, 32);
            const float x = fabsf(s + b3v);
            if (lane < 16)
                out[(size_t)(n0 + ct*16 + lane)*128 + d] = x;
        }
    }
}

// ---- fallback fused kernel (round-9 path) if ws too small -----------------
__global__ __launch_bounds__(64, 4) void decoder_mfma(
    const float* __restrict__ z,
    const __hip_bfloat16* __restrict__ wp_hi, const __hip_bfloat16* __restrict__ wp_lo,
    const __hip_bfloat16* __restrict__ w2_hi, const __hip_bfloat16* __restrict__ w2_lo,
    const float* __restrict__ W1, const float* __restrict__ b1,
    const float* __restrict__ b2,
    const float* __restrict__ W3, const float* __restrict__ b3,
    float* __restrict__ out)
{
    __shared__ float Y[64][33];

    const int lane = threadIdx.x;
    const int l15  = lane & 15;
    const int lg   = lane >> 4;
    const int g    = blockIdx.x & 3;
    const int n0   = (blockIdx.x >> 2) * 64;

    bf16x8 wh[2][2], wl[2][2];
    #pragma unroll
    for (int dt = 0; dt < 2; ++dt) {
        const int d = g*32 + dt*16 + l15;
        #pragma unroll
        for (int kt = 0; kt < 2; ++kt) {
            const int off = d*64 + kt*32 + lg*8;
            wh[dt][kt] = *(const bf16x8*)(wp_hi + off);
            wl[dt][kt] = *(const bf16x8*)(wp_lo + off);
        }
    }
    #pragma unroll
    for (int nt = 0; nt < 4; ++nt) {
        bf16x8 zh[2], zl[2];
        #pragma unroll
        for (int kt = 0; kt < 2; ++kt) {
            const float* p = z + (size_t)(n0 + nt*16 + l15)*64 + kt*32 + lg*8;
            split8(*(const f32x4*)p, *(const f32x4*)(p + 4), zh[kt], zl[kt]);
        }
        #pragma unroll
        for (int dt = 0; dt < 2; ++dt) {
            f32x4 acc = {0.f, 0.f, 0.f, 0.f};
            #pragma unroll
            for (int kt = 0; kt < 2; ++kt) {
                acc = MFMA(zh[kt], wh[dt][kt], acc);
                acc = MFMA(zl[kt], wh[dt][kt], acc);
                acc = MFMA(zh[kt], wl[dt][kt], acc);
            }
            #pragma unroll
            for (int r = 0; r < 4; ++r)
                Y[nt*16 + lg*4 + r][dt*16 + l15] = acc[r];
        }
    }
    __syncthreads();

    #pragma unroll 4
    for (int j = 0; j < 32; ++j) {
        const int d = g*32 + j;
        bf16x8 ah[2], al[2];
        #pragma unroll
        for (int rt = 0; rt < 2; ++rt) {
            const int off = d*1024 + (rt*16 + l15)*32 + lg*8;
            ah[rt] = *(const bf16x8*)(w2_hi + off);
            al[rt] = *(const bf16x8*)(w2_lo + off);
        }
        const f32x4 w1a = *(const f32x4*)(W1 + d*32 + lg*8);
        const f32x4 w1b = *(const f32x4*)(W1 + d*32 + lg*8 + 4);
        const f32x4 b1a = *(const f32x4*)(b1 + d*32 + lg*8);
        const f32x4 b1b = *(const f32x4*)(b1 + d*32 + lg*8 + 4);
        const f32x4 b2a = *(const f32x4*)(b2 + d*32 + lg*4);
        const f32x4 b2b = *(const f32x4*)(b2 + d*32 + 16 + lg*4);
        const f32x4 w3a = *(const f32x4*)(W3 + d*32 + lg*4);
        const f32x4 w3b = *(const f32x4*)(W3 + d*32 + 16 + lg*4);
        const float b3v = b3[d];

        float yv[4];
        #pragma unroll
        for (int ct = 0; ct < 4; ++ct) yv[ct] = Y[ct*16 + l15][j];

        bf16x8 pk[4];
        #pragma unroll
        for (int ct = 0; ct < 4; ++ct) {
            const float y = yv[ct];
            float h0[4], h1v[4];
            #pragma unroll
            for (int i = 0; i < 4; ++i) h0[i]  = fmaxf(fmaf(y, w1a[i], b1a[i]), 0.f);
            #pragma unroll
            for (int i = 0; i < 4; ++i) h1v[i] = fmaxf(fmaf(y, w1b[i], b1b[i]), 0.f);
            BF8 r;
            r.h2[0] = __float22bfloat162_rn(make_float2(h0[0], h0[1]));
            r.h2[1] = __float22bfloat162_rn(make_float2(h0[2], h0[3]));
            r.h2[2] = __float22bfloat162_rn(make_float2(h1v[0], h1v[1]));
            r.h2[3] = __float22bfloat162_rn(make_float2(h1v[2], h1v[3]));
            pk[ct] = r.v;
        }

        f32x4 A0[4], A1[4];
        #pragma unroll
        for (int ct = 0; ct < 4; ++ct) { A0[ct] = b2a; A1[ct] = b2b; }
        #pragma unroll
        for (int ct = 0; ct < 4; ++ct) {
            A0[ct] = MFMA(ah[0], pk[ct], A0[ct]);
            A1[ct] = MFMA(ah[1], pk[ct], A1[ct]);
        }
        #pragma unroll
        for (int ct = 0; ct < 4; ++ct) {
            A0[ct] = MFMA(al[0], pk[ct], A0[ct]);
            A1[ct] = MFMA(al[1], pk[ct], A1[ct]);
        }

        #pragma unroll
        for (int ct = 0; ct < 4; ++ct) {
            float s = fmaxf(A0[ct][0], 0.f) * w3a[0];
            s = fmaf(fmaxf(A0[ct][1], 0.f), w3a[1], s);
            s = fmaf(fmaxf(A0[ct][2], 0.f), w3a[2], s);
            s = fmaf(fmaxf(A0[ct][3], 0.f), w3a[3], s);
            s = fmaf(fmaxf(A1[ct][0], 0.f), w3b[0], s);
            s = fmaf(fmaxf(A1[ct][1], 0.f), w3b[1], s);
            s = fmaf(fmaxf(A1[ct][2], 0.f), w3b[2], s);
            s = fmaf(fmaxf(A1[ct][3], 0.f), w3b[3], s);
            s += __shfl_xor(s, 16);
            s += __shfl_xor(s, 32);
            const float x = fabsf(s + b3v);
            if (lane < 16) Y[ct*16 + lane][j] = x;
        }
    }
    __syncthreads();

    const int cg = lane & 7;
    #pragma unroll
    for (int it = 0; it < 8; ++it) {
        const int n = it*8 + (lane >> 3);
        f32x4 v;
        #pragma unroll
        for (int c = 0; c < 4; ++c) v[c] = Y[n][cg*4 + c];
        *(f32x4*)(out + (size_t)(n0 + n)*128 + g*32 + cg*4) = v;
    }
}

extern "C" void kernel_launch(void* const* d_in, const int* in_sizes, int n_in,
                              void* d_out, int out_size, void* d_ws, size_t ws_size,
                              hipStream_t stream) {
    const float* z  = (const float*)d_in[0];
    const float* Wp = (const float*)d_in[1];
    const float* W1 = (const float*)d_in[2];
    const float* b1 = (const float*)d_in[3];
    const float* W2 = (const float*)d_in[4];
    const float* b2 = (const float*)d_in[5];
    const float* W3 = (const float*)d_in[6];
    const float* b3 = (const float*)d_in[7];
    float* out = (float*)d_out;

    __hip_bfloat16* wp_hi = (__hip_bfloat16*)d_ws;
    __hip_bfloat16* wp_lo = wp_hi + 128 * 64;
    __hip_bfloat16* w2_hi = wp_lo + 128 * 64;
    __hip_bfloat16* w2_lo = w2_hi + 128 * 1024;
    float* Yt = (float*)((char*)d_ws + 544 * 1024);        // 33.5 MB transposed Y
    const size_t need = 544 * 1024 + (size_t)128 * 65536 * 4;

    hipLaunchKernelGGL(split_weights, dim3(512), dim3(256), 0, stream,
                       Wp, W2, wp_hi, wp_lo, w2_hi, w2_lo);
    if (ws_size >= need) {
        hipLaunchKernelGGL(decoder_y, dim3(1024), dim3(256), 0, stream,
                           z, wp_hi, wp_lo, Yt);
        hipLaunchKernelGGL(decoder_mlp, dim3(1024), dim3(256), 0, stream,
                           Yt, w2_hi, w2_lo, W1, b1, b2, W3, b3, out);
    } else {
        hipLaunchKernelGGL(decoder_mfma, dim3(4096), dim3(64), 0, stream,
                           z, wp_hi, wp_lo, w2_hi, w2_lo, W1, b1, b2, W3, b3, out);
    }
}

// Round 11
// 101.018 us; speedup vs baseline: 2.8296x; 2.8296x over previous
//
#include <hip/hip_runtime.h>
#include <hip/hip_bf16.h>

typedef unsigned int uint32;
typedef __attribute__((ext_vector_type(8))) short bf16x8;
typedef __attribute__((ext_vector_type(4))) float f32x4;

#define MFMA(A, B, C) __builtin_amdgcn_mfma_f32_16x16x32_bf16(A, B, C, 0, 0, 0)

union FragU { uint32 u[4]; bf16x8 v; };
union BF8  { __hip_bfloat162 h2[4]; bf16x8 v; };

// 3-pass split (phase-1 z only): hi=trunc top16, lo=bf16(x-hi)
__device__ __forceinline__ void split8(f32x4 a, f32x4 b, bf16x8& hi, bf16x8& lo) {
    float e[8] = {a[0], a[1], a[2], a[3], b[0], b[1], b[2], b[3]};
    FragU H, L;
    #pragma unroll
    for (int q = 0; q < 4; ++q) {
        uint32 u0 = __float_as_uint(e[2*q]);
        uint32 u1 = __float_as_uint(e[2*q + 1]);
        uint32 h0 = u0 & 0xFFFF0000u;
        uint32 h1 = u1 & 0xFFFF0000u;
        float l0 = e[2*q]     - __uint_as_float(h0);
        float l1 = e[2*q + 1] - __uint_as_float(h1);
        H.u[q] = (h0 >> 16) | h1;
        L.u[q] = (__float_as_uint(l0) >> 16) | (__float_as_uint(l1) & 0xFFFF0000u);
    }
    hi = H.v; lo = L.v;
}

// ---- pre-kernel: split |Wp| and W2 into RNE hi/lo bf16 pairs in d_ws ----
__global__ __launch_bounds__(256) void split_weights(
    const float* __restrict__ Wp, const float* __restrict__ W2,
    __hip_bfloat16* __restrict__ wp_hi, __hip_bfloat16* __restrict__ wp_lo,
    __hip_bfloat16* __restrict__ w2_hi, __hip_bfloat16* __restrict__ w2_lo)
{
    const int i = blockIdx.x * 256 + threadIdx.x;
    if (i < 128 * 64) {
        float x = fabsf(Wp[i]);
        __hip_bfloat16 h = __float2bfloat16(x);          // RNE
        wp_hi[i] = h;
        wp_lo[i] = __float2bfloat16(x - __bfloat162float(h));
    }
    if (i < 128 * 1024) {
        float x = W2[i];
        __hip_bfloat16 h = __float2bfloat16(x);
        w2_hi[i] = h;
        w2_lo[i] = __float2bfloat16(x - __bfloat162float(h));
    }
}

// Per-feature weight set, double-buffered across j for software prefetch.
struct WB { bf16x8 ah0, ah1, al0, al1; f32x4 w1a, w1b, b1a, b1b; };

__device__ __forceinline__ WB load_wb(int d, int l15, int lg,
        const __hip_bfloat16* __restrict__ w2_hi,
        const __hip_bfloat16* __restrict__ w2_lo,
        const float* __restrict__ W1, const float* __restrict__ b1)
{
    WB w;
    const int o0 = d*1024 + l15*32 + lg*8;          // k2 row l15
    const int o1 = o0 + 16*32;                      // k2 row 16+l15
    w.ah0 = *(const bf16x8*)(w2_hi + o0);
    w.ah1 = *(const bf16x8*)(w2_hi + o1);
    w.al0 = *(const bf16x8*)(w2_lo + o0);
    w.al1 = *(const bf16x8*)(w2_lo + o1);
    w.w1a = *(const f32x4*)(W1 + d*32 + lg*8);
    w.w1b = *(const f32x4*)(W1 + d*32 + lg*8 + 4);
    w.b1a = *(const f32x4*)(b1 + d*32 + lg*8);
    w.b1b = *(const f32x4*)(b1 + d*32 + lg*8 + 4);
    return w;
}

// 1 wave per block: 64 samples x 32 features (r9 structure).
// Phase 2 is software-pipelined: weights for feature j+1 are loaded (13 VMEM,
// ~200cyc L2 latency) while feature j computes. launch_bounds(64,3) allows
// up to 168 VGPR -- the 16-WG/CU cap means this costs no occupancy.
__global__ __launch_bounds__(64, 3) void decoder_mfma(
    const float* __restrict__ z,
    const __hip_bfloat16* __restrict__ wp_hi, const __hip_bfloat16* __restrict__ wp_lo,
    const __hip_bfloat16* __restrict__ w2_hi, const __hip_bfloat16* __restrict__ w2_lo,
    const float* __restrict__ W1, const float* __restrict__ b1,
    const float* __restrict__ b2,
    const float* __restrict__ W3, const float* __restrict__ b3,
    float* __restrict__ out)
{
    __shared__ float Y[64][33];      // 8448 B, +1 pad

    const int lane = threadIdx.x;    // 0..63
    const int l15  = lane & 15;
    const int lg   = lane >> 4;
    const int g    = blockIdx.x & 3;           // feature group: [32g, 32g+32)
    const int n0   = (blockIdx.x >> 2) * 64;   // sample tile

    // ---------------- Phase 1: Y = z @ |Wp|^T -----------------------------
    bf16x8 wh[2][2], wl[2][2];
    #pragma unroll
    for (int dt = 0; dt < 2; ++dt) {
        const int d = g*32 + dt*16 + l15;
        #pragma unroll
        for (int kt = 0; kt < 2; ++kt) {
            const int off = d*64 + kt*32 + lg*8;
            wh[dt][kt] = *(const bf16x8*)(wp_hi + off);
            wl[dt][kt] = *(const bf16x8*)(wp_lo + off);
        }
    }
    #pragma unroll
    for (int nt = 0; nt < 4; ++nt) {
        bf16x8 zh[2], zl[2];
        #pragma unroll
        for (int kt = 0; kt < 2; ++kt) {
            const float* p = z + (size_t)(n0 + nt*16 + l15)*64 + kt*32 + lg*8;
            split8(*(const f32x4*)p, *(const f32x4*)(p + 4), zh[kt], zl[kt]);
        }
        #pragma unroll
        for (int dt = 0; dt < 2; ++dt) {
            f32x4 acc = {0.f, 0.f, 0.f, 0.f};
            #pragma unroll
            for (int kt = 0; kt < 2; ++kt) {
                acc = MFMA(zh[kt], wh[dt][kt], acc);   // hi*hi
                acc = MFMA(zl[kt], wh[dt][kt], acc);   // lo*hi
                acc = MFMA(zh[kt], wl[dt][kt], acc);   // hi*lo
            }
            #pragma unroll
            for (int r = 0; r < 4; ++r)
                Y[nt*16 + lg*4 + r][dt*16 + l15] = acc[r];
        }
    }
    __syncthreads();

    // ---------------- Phase 2: pipelined per-feature tiny MLP -------------
    auto COMPUTE = [&](int j, const WB& w) {
        const int d = g*32 + j;
        // tail weights: issue early, consumed after the MFMAs
        const f32x4 b2a = *(const f32x4*)(b2 + d*32 + lg*4);
        const f32x4 b2b = *(const f32x4*)(b2 + d*32 + 16 + lg*4);
        const f32x4 w3a = *(const f32x4*)(W3 + d*32 + lg*4);
        const f32x4 w3b = *(const f32x4*)(W3 + d*32 + 16 + lg*4);
        const float b3v = b3[d];

        float yv[4];
        #pragma unroll
        for (int ct = 0; ct < 4; ++ct) yv[ct] = Y[ct*16 + l15][j];

        bf16x8 pk[4];
        #pragma unroll
        for (int ct = 0; ct < 4; ++ct) {
            const float y = yv[ct];
            float h0[4], h1v[4];
            #pragma unroll
            for (int i = 0; i < 4; ++i) h0[i]  = fmaxf(fmaf(y, w.w1a[i], w.b1a[i]), 0.f);
            #pragma unroll
            for (int i = 0; i < 4; ++i) h1v[i] = fmaxf(fmaf(y, w.w1b[i], w.b1b[i]), 0.f);
            BF8 r;
            r.h2[0] = __float22bfloat162_rn(make_float2(h0[0], h0[1]));
            r.h2[1] = __float22bfloat162_rn(make_float2(h0[2], h0[3]));
            r.h2[2] = __float22bfloat162_rn(make_float2(h1v[0], h1v[1]));
            r.h2[3] = __float22bfloat162_rn(make_float2(h1v[2], h1v[3]));
            pk[ct] = r.v;
        }

        f32x4 A0[4], A1[4];
        #pragma unroll
        for (int ct = 0; ct < 4; ++ct) { A0[ct] = b2a; A1[ct] = b2b; }
        __builtin_amdgcn_s_setprio(1);
        #pragma unroll
        for (int ct = 0; ct < 4; ++ct) {
            A0[ct] = MFMA(w.ah0, pk[ct], A0[ct]);
            A1[ct] = MFMA(w.ah1, pk[ct], A1[ct]);
        }
        #pragma unroll
        for (int ct = 0; ct < 4; ++ct) {
            A0[ct] = MFMA(w.al0, pk[ct], A0[ct]);
            A1[ct] = MFMA(w.al1, pk[ct], A1[ct]);
        }
        __builtin_amdgcn_s_setprio(0);

        #pragma unroll
        for (int ct = 0; ct < 4; ++ct) {
            float s = fmaxf(A0[ct][0], 0.f) * w3a[0];
            s = fmaf(fmaxf(A0[ct][1], 0.f), w3a[1], s);
            s = fmaf(fmaxf(A0[ct][2], 0.f), w3a[2], s);
            s = fmaf(fmaxf(A0[ct][3], 0.f), w3a[3], s);
            s = fmaf(fmaxf(A1[ct][0], 0.f), w3b[0], s);
            s = fmaf(fmaxf(A1[ct][1], 0.f), w3b[1], s);
            s = fmaf(fmaxf(A1[ct][2], 0.f), w3b[2], s);
            s = fmaf(fmaxf(A1[ct][3], 0.f), w3b[3], s);
            s += __shfl_xor(s, 16);      // reduce over the 4 lg groups
            s += __shfl_xor(s, 32);
            const float x = fabsf(s + b3v);
            if (lane < 16) Y[ct*16 + lane][j] = x;
        }
    };

    WB wA = load_wb(g*32, l15, lg, w2_hi, w2_lo, W1, b1);
    #pragma unroll 1
    for (int jj = 0; jj < 32; jj += 2) {
        WB wB = load_wb(g*32 + jj + 1, l15, lg, w2_hi, w2_lo, W1, b1);  // prefetch j+1
        COMPUTE(jj, wA);
        wA = load_wb(g*32 + ((jj + 2) & 31), l15, lg, w2_hi, w2_lo, W1, b1); // prefetch j+2
        COMPUTE(jj + 1, wB);
    }
    __syncthreads();

    // ---------------- coalesced copy-out ----------------------------------
    const int cg = lane & 7;
    #pragma unroll
    for (int it = 0; it < 8; ++it) {
        const int n = it*8 + (lane >> 3);
        f32x4 v;
        #pragma unroll
        for (int c = 0; c < 4; ++c) v[c] = Y[n][cg*4 + c];
        *(f32x4*)(out + (size_t)(n0 + n)*128 + g*32 + cg*4) = v;
    }
}

extern "C" void kernel_launch(void* const* d_in, const int* in_sizes, int n_in,
                              void* d_out, int out_size, void* d_ws, size_t ws_size,
                              hipStream_t stream) {
    const float* z  = (const float*)d_in[0];
    const float* Wp = (const float*)d_in[1];
    const float* W1 = (const float*)d_in[2];
    const float* b1 = (const float*)d_in[3];
    const float* W2 = (const float*)d_in[4];
    const float* b2 = (const float*)d_in[5];
    const float* W3 = (const float*)d_in[6];
    const float* b3 = (const float*)d_in[7];
    float* out = (float*)d_out;

    __hip_bfloat16* wp_hi = (__hip_bfloat16*)d_ws;
    __hip_bfloat16* wp_lo = wp_hi + 128 * 64;
    __hip_bfloat16* w2_hi = wp_lo + 128 * 64;
    __hip_bfloat16* w2_lo = w2_hi + 128 * 1024;

    hipLaunchKernelGGL(split_weights, dim3(512), dim3(256), 0, stream,
                       Wp, W2, wp_hi, wp_lo, w2_hi, w2_lo);
    // 4096 one-wave blocks: bid&3 = feature group, bid>>2 = sample tile
    hipLaunchKernelGGL(decoder_mfma, dim3(4096), dim3(64), 0, stream,
                       z, wp_hi, wp_lo, w2_hi, w2_lo, W1, b1, b2, W3, b3, out);
}

// Round 12
// 99.823 us; speedup vs baseline: 2.8635x; 1.0120x over previous
//
#include <hip/hip_runtime.h>
#include <hip/hip_bf16.h>

typedef unsigned int uint32;
typedef __attribute__((ext_vector_type(8))) short bf16x8;
typedef __attribute__((ext_vector_type(4))) float f32x4;

#define MFMA(A, B, C) __builtin_amdgcn_mfma_f32_16x16x32_bf16(A, B, C, 0, 0, 0)

union FragU { uint32 u[4]; bf16x8 v; };
union BF8  { __hip_bfloat162 h2[4]; bf16x8 v; };

// 3-pass split (phase-1 z only): hi=trunc top16, lo=bf16(x-hi)
__device__ __forceinline__ void split8(f32x4 a, f32x4 b, bf16x8& hi, bf16x8& lo) {
    float e[8] = {a[0], a[1], a[2], a[3], b[0], b[1], b[2], b[3]};
    FragU H, L;
    #pragma unroll
    for (int q = 0; q < 4; ++q) {
        uint32 u0 = __float_as_uint(e[2*q]);
        uint32 u1 = __float_as_uint(e[2*q + 1]);
        uint32 h0 = u0 & 0xFFFF0000u;
        uint32 h1 = u1 & 0xFFFF0000u;
        float l0 = e[2*q]     - __uint_as_float(h0);
        float l1 = e[2*q + 1] - __uint_as_float(h1);
        H.u[q] = (h0 >> 16) | h1;
        L.u[q] = (__float_as_uint(l0) >> 16) | (__float_as_uint(l1) & 0xFFFF0000u);
    }
    hi = H.v; lo = L.v;
}

// ---- pre-kernel: split |Wp| and W2 into RNE hi/lo bf16 pairs in d_ws ----
__global__ __launch_bounds__(256) void split_weights(
    const float* __restrict__ Wp, const float* __restrict__ W2,
    __hip_bfloat16* __restrict__ wp_hi, __hip_bfloat16* __restrict__ wp_lo,
    __hip_bfloat16* __restrict__ w2_hi, __hip_bfloat16* __restrict__ w2_lo)
{
    const int i = blockIdx.x * 256 + threadIdx.x;
    if (i < 128 * 64) {
        float x = fabsf(Wp[i]);
        __hip_bfloat16 h = __float2bfloat16(x);          // RNE
        wp_hi[i] = h;
        wp_lo[i] = __float2bfloat16(x - __bfloat162float(h));
    }
    if (i < 128 * 1024) {
        float x = W2[i];
        __hip_bfloat16 h = __float2bfloat16(x);
        w2_hi[i] = h;
        w2_lo[i] = __float2bfloat16(x - __bfloat162float(h));
    }
}

// Feature-resident decomposition. Block = 1024 thr = 16 waves.
// bid&7 -> feature group dbase = 16 features; bid>>3 -> 512-sample group.
// Phase 1: block computes Ylds[512][16] via swapped MFMA (A=Wp rows -> D row=d).
// Phase 2: wave w owns feature d=dbase+w; weights in registers ONCE; streams
//          8 x 64-sample tiles from LDS. Output transposed via XT for full-line
//          coalesced stores (16 thr = 64B).
__global__ __launch_bounds__(1024, 4) void decoder_fused2(
    const float* __restrict__ z,
    const __hip_bfloat16* __restrict__ wp_hi, const __hip_bfloat16* __restrict__ wp_lo,
    const __hip_bfloat16* __restrict__ w2_hi, const __hip_bfloat16* __restrict__ w2_lo,
    const float* __restrict__ W1, const float* __restrict__ b1,
    const float* __restrict__ b2,
    const float* __restrict__ W3, const float* __restrict__ b3,
    float* __restrict__ out)
{
    __shared__ float Ylds[512][17];     // 34.8 KB, stride 17: conflict-free
    __shared__ float XT[2][64][17];     // 8.7 KB, parity double-buffer

    const int t    = threadIdx.x;
    const int lane = t & 63;
    const int w    = __builtin_amdgcn_readfirstlane(t >> 6);  // 0..15
    const int l15  = lane & 15;
    const int lg   = lane >> 4;
    const int dbase = (blockIdx.x & 7) * 16;
    const int nbase = (blockIdx.x >> 3) * 512;

    // ---------------- Phase 1: Ylds[n][d] = z . |Wp|^T --------------------
    {
        // A-frags: Wp rows d = dbase+l15 (output ROW = d)
        bf16x8 ph[2], pl[2];
        #pragma unroll
        for (int kt = 0; kt < 2; ++kt) {
            const int off = (dbase + l15)*64 + kt*32 + lg*8;
            ph[kt] = *(const bf16x8*)(wp_hi + off);
            pl[kt] = *(const bf16x8*)(wp_lo + off);
        }
        #pragma unroll
        for (int nt2 = 0; nt2 < 2; ++nt2) {
            const int nb = w*32 + nt2*16;            // wave's sample subtile
            bf16x8 zh[2], zl[2];
            #pragma unroll
            for (int kt = 0; kt < 2; ++kt) {
                const float* p = z + (size_t)(nbase + nb + l15)*64 + kt*32 + lg*8;
                split8(*(const f32x4*)p, *(const f32x4*)(p + 4), zh[kt], zl[kt]);
            }
            f32x4 acc = {0.f, 0.f, 0.f, 0.f};
            #pragma unroll
            for (int kt = 0; kt < 2; ++kt) {
                acc = MFMA(ph[kt], zh[kt], acc);   // hi*hi
                acc = MFMA(pl[kt], zh[kt], acc);   // lo*hi
                acc = MFMA(ph[kt], zl[kt], acc);   // hi*lo
            }
            // D: row = d-offset = lg*4+r, col = sample = l15
            #pragma unroll
            for (int r = 0; r < 4; ++r)
                Ylds[nb + l15][lg*4 + r] = acc[r];
        }
    }
    __syncthreads();

    // ---------------- Phase 2: wave-resident feature d = dbase + w --------
    const int d = dbase + w;
    // one-time weight load (L2-resident after first blocks)
    bf16x8 ah0, ah1, al0, al1;
    {
        const int o0 = d*1024 + l15*32 + lg*8;       // k2 row l15
        const int o1 = o0 + 16*32;                   // k2 row 16+l15
        ah0 = *(const bf16x8*)(w2_hi + o0);
        ah1 = *(const bf16x8*)(w2_hi + o1);
        al0 = *(const bf16x8*)(w2_lo + o0);
        al1 = *(const bf16x8*)(w2_lo + o1);
    }
    const f32x4 w1a = *(const f32x4*)(W1 + d*32 + lg*8);
    const f32x4 w1b = *(const f32x4*)(W1 + d*32 + lg*8 + 4);
    const f32x4 b1a = *(const f32x4*)(b1 + d*32 + lg*8);
    const f32x4 b1b = *(const f32x4*)(b1 + d*32 + lg*8 + 4);
    const f32x4 b2a = *(const f32x4*)(b2 + d*32 + lg*4);         // k2 = lg*4+r
    const f32x4 b2b = *(const f32x4*)(b2 + d*32 + 16 + lg*4);
    const f32x4 w3a = *(const f32x4*)(W3 + d*32 + lg*4);
    const f32x4 w3b = *(const f32x4*)(W3 + d*32 + 16 + lg*4);
    const float b3v = b3[d];

    #pragma unroll 1
    for (int st = 0; st < 8; ++st) {
        const int p = st & 1;

        // y column for this wave's feature: broadcast over lg, stride-17 rows
        float yv[4];
        #pragma unroll
        for (int ct = 0; ct < 4; ++ct) yv[ct] = Ylds[st*64 + ct*16 + l15][w];

        // 4 independent layer1 + pack chains
        bf16x8 pk[4];
        #pragma unroll
        for (int ct = 0; ct < 4; ++ct) {
            const float y = yv[ct];
            float h0[4], h1v[4];
            #pragma unroll
            for (int i = 0; i < 4; ++i) h0[i]  = fmaxf(fmaf(y, w1a[i], b1a[i]), 0.f);
            #pragma unroll
            for (int i = 0; i < 4; ++i) h1v[i] = fmaxf(fmaf(y, w1b[i], b1b[i]), 0.f);
            BF8 r;
            r.h2[0] = __float22bfloat162_rn(make_float2(h0[0], h0[1]));
            r.h2[1] = __float22bfloat162_rn(make_float2(h0[2], h0[3]));
            r.h2[2] = __float22bfloat162_rn(make_float2(h1v[0], h1v[1]));
            r.h2[3] = __float22bfloat162_rn(make_float2(h1v[2], h1v[3]));
            pk[ct] = r.v;
        }

        // 16 MFMAs (acc init = b2): 8 hi then 8 lo
        f32x4 A0[4], A1[4];
        #pragma unroll
        for (int ct = 0; ct < 4; ++ct) { A0[ct] = b2a; A1[ct] = b2b; }
        #pragma unroll
        for (int ct = 0; ct < 4; ++ct) {
            A0[ct] = MFMA(ah0, pk[ct], A0[ct]);
            A1[ct] = MFMA(ah1, pk[ct], A1[ct]);
        }
        #pragma unroll
        for (int ct = 0; ct < 4; ++ct) {
            A0[ct] = MFMA(al0, pk[ct], A0[ct]);
            A1[ct] = MFMA(al1, pk[ct], A1[ct]);
        }

        // layer-3 tails -> stage into XT
        #pragma unroll
        for (int ct = 0; ct < 4; ++ct) {
            float s = fmaxf(A0[ct][0], 0.f) * w3a[0];
            s = fmaf(fmaxf(A0[ct][1], 0.f), w3a[1], s);
            s = fmaf(fmaxf(A0[ct][2], 0.f), w3a[2], s);
            s = fmaf(fmaxf(A0[ct][3], 0.f), w3a[3], s);
            s = fmaf(fmaxf(A1[ct][0], 0.f), w3b[0], s);
            s = fmaf(fmaxf(A1[ct][1], 0.f), w3b[1], s);
            s = fmaf(fmaxf(A1[ct][2], 0.f), w3b[2], s);
            s = fmaf(fmaxf(A1[ct][3], 0.f), w3b[3], s);
            s += __shfl_xor(s, 16);      // reduce over the 4 lg groups
            s += __shfl_xor(s, 32);
            const float x = fabsf(s + b3v);
            if (lane < 16) XT[p][ct*16 + lane][w] = x;
        }
        __syncthreads();   // XT[p] complete for all 16 features

        // cooperative full-line store: 16 consecutive thr = 64B of one row
        out[(size_t)(nbase + st*64 + (t >> 4))*128 + dbase + (t & 15)]
            = XT[p][t >> 4][t & 15];
        // no trailing barrier: next tile writes XT[p^1]; XT[p] reuse at st+2
        // is fenced by the st+1 barrier.
    }
}

extern "C" void kernel_launch(void* const* d_in, const int* in_sizes, int n_in,
                              void* d_out, int out_size, void* d_ws, size_t ws_size,
                              hipStream_t stream) {
    const float* z  = (const float*)d_in[0];
    const float* Wp = (const float*)d_in[1];
    const float* W1 = (const float*)d_in[2];
    const float* b1 = (const float*)d_in[3];
    const float* W2 = (const float*)d_in[4];
    const float* b2 = (const float*)d_in[5];
    const float* W3 = (const float*)d_in[6];
    const float* b3 = (const float*)d_in[7];
    float* out = (float*)d_out;

    __hip_bfloat16* wp_hi = (__hip_bfloat16*)d_ws;
    __hip_bfloat16* wp_lo = wp_hi + 128 * 64;
    __hip_bfloat16* w2_hi = wp_lo + 128 * 64;
    __hip_bfloat16* w2_lo = w2_hi + 128 * 1024;

    hipLaunchKernelGGL(split_weights, dim3(512), dim3(256), 0, stream,
                       Wp, W2, wp_hi, wp_lo, w2_hi, w2_lo);
    // 128 sample-groups x 8 feature-groups
    hipLaunchKernelGGL(decoder_fused2, dim3(1024), dim3(1024), 0, stream,
                       z, wp_hi, wp_lo, w2_hi, w2_lo, W1, b1, b2, W3, b3, out);
}

// Round 13
// 65.773 us; speedup vs baseline: 4.3459x; 1.5177x over previous
//
#include <hip/hip_runtime.h>
#include <hip/hip_bf16.h>

typedef unsigned int uint32;
typedef __attribute__((ext_vector_type(8))) short    bf16x8;
typedef __attribute__((ext_vector_type(4))) float    f32x4;
typedef __attribute__((ext_vector_type(8))) _Float16 f16x8;
typedef __attribute__((ext_vector_type(2))) _Float16 f16x2;

#define MFMA_BF(A, B, C) __builtin_amdgcn_mfma_f32_16x16x32_bf16(A, B, C, 0, 0, 0)
#define MFMA_F16(A, B, C) __builtin_amdgcn_mfma_f32_16x16x32_f16(A, B, C, 0, 0, 0)

union FragU { uint32 u[4]; bf16x8 v; };
union H8    { f16x2 h[4]; f16x8 v; };

// 3-pass split (phase-1 z only): hi=trunc top16, lo=bf16(x-hi)
__device__ __forceinline__ void split8(f32x4 a, f32x4 b, bf16x8& hi, bf16x8& lo) {
    float e[8] = {a[0], a[1], a[2], a[3], b[0], b[1], b[2], b[3]};
    FragU H, L;
    #pragma unroll
    for (int q = 0; q < 4; ++q) {
        uint32 u0 = __float_as_uint(e[2*q]);
        uint32 u1 = __float_as_uint(e[2*q + 1]);
        uint32 h0 = u0 & 0xFFFF0000u;
        uint32 h1 = u1 & 0xFFFF0000u;
        float l0 = e[2*q]     - __uint_as_float(h0);
        float l1 = e[2*q + 1] - __uint_as_float(h1);
        H.u[q] = (h0 >> 16) | h1;
        L.u[q] = (__float_as_uint(l0) >> 16) | (__float_as_uint(l1) & 0xFFFF0000u);
    }
    hi = H.v; lo = L.v;
}

// ---- pre-kernel: |Wp| -> bf16 hi/lo; W2 -> fp16; W1,b1 -> packed f16x2 ----
__global__ __launch_bounds__(256) void split_weights(
    const float* __restrict__ Wp, const float* __restrict__ W2,
    const float* __restrict__ W1, const float* __restrict__ b1,
    __hip_bfloat16* __restrict__ wp_hi, __hip_bfloat16* __restrict__ wp_lo,
    _Float16* __restrict__ w2h, f16x2* __restrict__ w1p, f16x2* __restrict__ b1p)
{
    const int i = blockIdx.x * 256 + threadIdx.x;
    if (i < 128 * 64) {
        float x = fabsf(Wp[i]);
        __hip_bfloat16 h = __float2bfloat16(x);          // RNE
        wp_hi[i] = h;
        wp_lo[i] = __float2bfloat16(x - __bfloat162float(h));
    }
    if (i < 128 * 1024) {
        w2h[i] = (_Float16)W2[i];                        // RNE
    }
    if (i < 128 * 16) {
        const int d = i >> 4, q = i & 15;
        f16x2 a, b;
        a[0] = (_Float16)W1[d*32 + 2*q];  a[1] = (_Float16)W1[d*32 + 2*q + 1];
        b[0] = (_Float16)b1[d*32 + 2*q];  b[1] = (_Float16)b1[d*32 + 2*q + 1];
        w1p[i] = a;  b1p[i] = b;
    }
}

// 1 wave per block (r9 structure): 64 samples x 32 features.
// Phase 1: Y = z @ |Wp|^T, 3-pass bf16 MFMA (accurate y) -> LDS Y[64][33].
// Phase 2 per j: layer1 in PACKED fp16 (pk_fma/pk_max) -> result IS the f16
//   MFMA B-frag (no pack step); layer2 = 8x mfma_f32_16x16x32_f16 with
//   single-pass fp16 W2 (acc init = b2); layer3 scalar f32 + shfl reduce.
__global__ __launch_bounds__(64, 4) void decoder_mfma(
    const float* __restrict__ z,
    const __hip_bfloat16* __restrict__ wp_hi, const __hip_bfloat16* __restrict__ wp_lo,
    const _Float16* __restrict__ w2h,
    const f16x2* __restrict__ w1p, const f16x2* __restrict__ b1p,
    const float* __restrict__ b2,
    const float* __restrict__ W3, const float* __restrict__ b3,
    float* __restrict__ out)
{
    __shared__ float Y[64][33];      // 8448 B, +1 pad

    const int lane = threadIdx.x;    // 0..63
    const int l15  = lane & 15;
    const int lg   = lane >> 4;
    const int g    = blockIdx.x & 3;           // feature group: [32g, 32g+32)
    const int n0   = (blockIdx.x >> 2) * 64;   // sample tile

    // ---------------- Phase 1: Y = z @ |Wp|^T -----------------------------
    bf16x8 wh[2][2], wl[2][2];
    #pragma unroll
    for (int dt = 0; dt < 2; ++dt) {
        const int d = g*32 + dt*16 + l15;
        #pragma unroll
        for (int kt = 0; kt < 2; ++kt) {
            const int off = d*64 + kt*32 + lg*8;
            wh[dt][kt] = *(const bf16x8*)(wp_hi + off);
            wl[dt][kt] = *(const bf16x8*)(wp_lo + off);
        }
    }
    #pragma unroll
    for (int nt = 0; nt < 4; ++nt) {
        bf16x8 zh[2], zl[2];
        #pragma unroll
        for (int kt = 0; kt < 2; ++kt) {
            const float* p = z + (size_t)(n0 + nt*16 + l15)*64 + kt*32 + lg*8;
            split8(*(const f32x4*)p, *(const f32x4*)(p + 4), zh[kt], zl[kt]);
        }
        #pragma unroll
        for (int dt = 0; dt < 2; ++dt) {
            f32x4 acc = {0.f, 0.f, 0.f, 0.f};
            #pragma unroll
            for (int kt = 0; kt < 2; ++kt) {
                acc = MFMA_BF(zh[kt], wh[dt][kt], acc);   // hi*hi
                acc = MFMA_BF(zl[kt], wh[dt][kt], acc);   // lo*hi
                acc = MFMA_BF(zh[kt], wl[dt][kt], acc);   // hi*lo
            }
            #pragma unroll
            for (int r = 0; r < 4; ++r)
                Y[nt*16 + lg*4 + r][dt*16 + l15] = acc[r];
        }
    }
    __syncthreads();

    // ---------------- Phase 2: per-feature tiny MLP (fp16 datapath) -------
    const f16x2 zero2 = {(_Float16)0.f, (_Float16)0.f};
    #pragma unroll 4
    for (int j = 0; j < 32; ++j) {
        const int d = g*32 + j;                  // wave-uniform feature
        // A-frags: fp16 W2[d] rows (k2 = l15 and 16+l15), k = h = lg*8+i
        const f16x8 ah0 = *(const f16x8*)(w2h + d*1024 + l15*32 + lg*8);
        const f16x8 ah1 = *(const f16x8*)(w2h + d*1024 + (16 + l15)*32 + lg*8);
        // layer-1 weights: 4 packed f16x2 per lane = one 16B load each
        H8 w1u, b1u;
        w1u.v = *(const f16x8*)(w1p + d*16 + lg*4);
        b1u.v = *(const f16x8*)(b1p + d*16 + lg*4);
        const f32x4 b2a = *(const f32x4*)(b2 + d*32 + lg*4);        // k2 = lg*4+r
        const f32x4 b2b = *(const f32x4*)(b2 + d*32 + 16 + lg*4);
        const f32x4 w3a = *(const f32x4*)(W3 + d*32 + lg*4);
        const f32x4 w3b = *(const f32x4*)(W3 + d*32 + 16 + lg*4);
        const float b3v = b3[d];

        // ---- 4 y reads issued together ----
        float yv[4];
        #pragma unroll
        for (int ct = 0; ct < 4; ++ct) yv[ct] = Y[ct*16 + l15][j];

        // ---- 4 independent packed-fp16 layer1 chains (no pack step!) ----
        f16x8 pk[4];
        #pragma unroll
        for (int ct = 0; ct < 4; ++ct) {
            const _Float16 yh = (_Float16)yv[ct];
            const f16x2 y2 = {yh, yh};
            H8 u;
            #pragma unroll
            for (int q = 0; q < 4; ++q)
                u.h[q] = __builtin_elementwise_max(
                             __builtin_elementwise_fma(y2, w1u.h[q], b1u.h[q]),
                             zero2);
            pk[ct] = u.v;
        }

        // ---- 8 f16 MFMAs (acc init = b2) ----
        f32x4 A0[4], A1[4];
        #pragma unroll
        for (int ct = 0; ct < 4; ++ct) { A0[ct] = b2a; A1[ct] = b2b; }
        #pragma unroll
        for (int ct = 0; ct < 4; ++ct) {
            A0[ct] = MFMA_F16(ah0, pk[ct], A0[ct]);
            A1[ct] = MFMA_F16(ah1, pk[ct], A1[ct]);
        }

        // ---- 4 independent layer3 tails ----
        #pragma unroll
        for (int ct = 0; ct < 4; ++ct) {
            float s = fmaxf(A0[ct][0], 0.f) * w3a[0];
            s = fmaf(fmaxf(A0[ct][1], 0.f), w3a[1], s);
            s = fmaf(fmaxf(A0[ct][2], 0.f), w3a[2], s);
            s = fmaf(fmaxf(A0[ct][3], 0.f), w3a[3], s);
            s = fmaf(fmaxf(A1[ct][0], 0.f), w3b[0], s);
            s = fmaf(fmaxf(A1[ct][1], 0.f), w3b[1], s);
            s = fmaf(fmaxf(A1[ct][2], 0.f), w3b[2], s);
            s = fmaf(fmaxf(A1[ct][3], 0.f), w3b[3], s);
            s += __shfl_xor(s, 16);      // reduce over the 4 lg groups
            s += __shfl_xor(s, 32);
            const float x = fabsf(s + b3v);
            if (lane < 16) Y[ct*16 + lane][j] = x;
        }
    }
    __syncthreads();

    // ---------------- coalesced copy-out ----------------------------------
    const int cg = lane & 7;
    #pragma unroll
    for (int it = 0; it < 8; ++it) {
        const int n = it*8 + (lane >> 3);
        f32x4 v;
        #pragma unroll
        for (int c = 0; c < 4; ++c) v[c] = Y[n][cg*4 + c];
        *(f32x4*)(out + (size_t)(n0 + n)*128 + g*32 + cg*4) = v;
    }
}

extern "C" void kernel_launch(void* const* d_in, const int* in_sizes, int n_in,
                              void* d_out, int out_size, void* d_ws, size_t ws_size,
                              hipStream_t stream) {
    const float* z  = (const float*)d_in[0];
    const float* Wp = (const float*)d_in[1];
    const float* W1 = (const float*)d_in[2];
    const float* b1 = (const float*)d_in[3];
    const float* W2 = (const float*)d_in[4];
    const float* b2 = (const float*)d_in[5];
    const float* W3 = (const float*)d_in[6];
    const float* b3 = (const float*)d_in[7];
    float* out = (float*)d_out;

    __hip_bfloat16* wp_hi = (__hip_bfloat16*)d_ws;          // 8192
    __hip_bfloat16* wp_lo = wp_hi + 128 * 64;               // 8192
    _Float16*       w2h   = (_Float16*)(wp_lo + 128 * 64);  // 131072
    f16x2*          w1p   = (f16x2*)(w2h + 128 * 1024);     // 2048
    f16x2*          b1p   = w1p + 128 * 16;                 // 2048

    hipLaunchKernelGGL(split_weights, dim3(512), dim3(256), 0, stream,
                       Wp, W2, W1, b1, wp_hi, wp_lo, w2h, w1p, b1p);
    // 4096 one-wave blocks: bid&3 = feature group, bid>>2 = sample tile
    hipLaunchKernelGGL(decoder_mfma, dim3(4096), dim3(64), 0, stream,
                       z, wp_hi, wp_lo, w2h, w1p, b1p, b2, W3, b3, out);
}